// Round 9
// baseline (739.331 us; speedup 1.0000x reference)
//
#include <hip/hip_runtime.h>
#include <hip/hip_bf16.h>

#define N_NODES 50000
#define N_EDGES 1600000
#define E2 (N_EDGES + N_NODES)
#define NB 782      // buckets of 64 dst nodes
#define BCAP 3072   // max edges per bucket (mean 2112, 21 sigma)
#define CHUNK 8192
#define NBLK_E 202  // ceil(E2 / CHUNK)
#define NS 7        // src slices of 8192 nodes (4 MB bf16 rows = one XCD L2)
#define RP2W 8      // rowptr2 row width: starts of s=0..6, slot 7 = row end
#define WPG 8192    // persistent-ish waves: 2048 blocks x 4
#define NPW 7       // nodes per wave: ceil(50000/8192)

typedef __attribute__((ext_vector_type(8))) short bf16x8;
typedef __attribute__((ext_vector_type(4))) float f32x4;

static __device__ __forceinline__ float lrelu(float x) { return x > 0.f ? x : 0.2f * x; }

static __device__ __forceinline__ float b2f(ushort u) {
    union { unsigned int u; float f; } v;
    v.u = ((unsigned int)u) << 16;
    return v.f;
}
static __device__ __forceinline__ float hi2f(unsigned int u) {
    union { unsigned int u; float f; } v;
    v.u = u & 0xffff0000u;
    return v.f;
}
static __device__ __forceinline__ float lo2f(unsigned int u) {
    union { unsigned int u; float f; } v;
    v.u = u << 16;
    return v.f;
}
static __device__ __forceinline__ ushort f2b(float f) {
    union { float f; unsigned int u; } v;
    v.f = f;
    unsigned int r = v.u + 0x7FFFu + ((v.u >> 16) & 1u);  // RNE
    return (ushort)(r >> 16);
}

// ---------------- CSR build: atomic-free 3-pass bucket sort ----------------

__global__ __launch_bounds__(256) void k_bhist(const int* __restrict__ edst, int* __restrict__ hist) {
    __shared__ int cnt[NB];
    int t = threadIdx.x;
    for (int i = t; i < NB; i += 256) cnt[i] = 0;
    __syncthreads();
    int e0 = blockIdx.x * CHUNK;
    int eend = min(e0 + CHUNK, E2);
    for (int e = e0 + t; e < eend; e += 256) {
        int d = (e < N_EDGES) ? edst[e] : (e - N_EDGES);
        atomicAdd(&cnt[d >> 6], 1);
    }
    __syncthreads();
    for (int i = t; i < NB; i += 256) hist[blockIdx.x * NB + i] = cnt[i];
}

__global__ __launch_bounds__(1024) void k_colscan(const int* __restrict__ hist,
                                                  int* __restrict__ start, int* __restrict__ btotal) {
    int b = threadIdx.x;
    if (b >= NB) return;
    int run = 0;
#pragma unroll 4
    for (int blk = 0; blk < NBLK_E; ++blk) {
        int v = hist[blk * NB + b];
        start[blk * NB + b] = run;
        run += v;
    }
    btotal[b] = run;
}

__global__ __launch_bounds__(256) void k_bscan(const int* __restrict__ btotal, int* __restrict__ bbase) {
    __shared__ int s[256];
    int t = threadIdx.x;
    int v[4];
    int sum = 0;
#pragma unroll
    for (int k = 0; k < 4; ++k) {
        int i = t * 4 + k;
        v[k] = (i < NB) ? btotal[i] : 0;
        sum += v[k];
    }
    s[t] = sum;
    __syncthreads();
    for (int off = 1; off < 256; off <<= 1) {
        int add = (t >= off) ? s[t - off] : 0;
        __syncthreads();
        s[t] += add;
        __syncthreads();
    }
    int base = s[t] - sum;
#pragma unroll
    for (int k = 0; k < 4; ++k) {
        int i = t * 4 + k;
        if (i < NB) bbase[i] = base;
        base += v[k];
    }
}

__global__ __launch_bounds__(256) void k_bscatter(const int* __restrict__ esrc, const int* __restrict__ edst,
                                                  const int* __restrict__ start, const int* __restrict__ bbase,
                                                  unsigned int* __restrict__ bbuf) {
    __shared__ int cnt[NB];
    __shared__ int cur[NB];
    __shared__ int gofs[NB];
    __shared__ int s_scan[256];
    __shared__ unsigned int s_e[CHUNK];
    int t = threadIdx.x;
    for (int i = t; i < NB; i += 256) cnt[i] = 0;
    __syncthreads();
    int e0 = blockIdx.x * CHUNK;
    int eend = min(e0 + CHUNK, E2);
    for (int e = e0 + t; e < eend; e += 256) {
        int d = (e < N_EDGES) ? edst[e] : (e - N_EDGES);
        atomicAdd(&cnt[d >> 6], 1);
    }
    __syncthreads();
    int v[4];
    int sum = 0;
#pragma unroll
    for (int k = 0; k < 4; ++k) {
        int i = t * 4 + k;
        v[k] = (i < NB) ? cnt[i] : 0;
        sum += v[k];
    }
    s_scan[t] = sum;
    __syncthreads();
    for (int off = 1; off < 256; off <<= 1) {
        int add = (t >= off) ? s_scan[t - off] : 0;
        __syncthreads();
        s_scan[t] += add;
        __syncthreads();
    }
    int run = s_scan[t] - sum;
#pragma unroll
    for (int k = 0; k < 4; ++k) {
        int i = t * 4 + k;
        if (i < NB) {
            cur[i] = run;
            gofs[i] = bbase[i] + start[blockIdx.x * NB + i] - run;
        }
        run += v[k];
    }
    __syncthreads();
    for (int e = e0 + t; e < eend; e += 256) {
        int s, d;
        if (e < N_EDGES) { s = esrc[e]; d = edst[e]; } else { s = d = e - N_EDGES; }
        int b = d >> 6;
        int pos = atomicAdd(&cur[b], 1);
        s_e[pos] = (unsigned int)s | ((unsigned int)(d & 63) << 16) | ((unsigned int)b << 22);
    }
    __syncthreads();
    int cntall = eend - e0;
    for (int i = t; i < cntall; i += 256) {
        unsigned int p = s_e[i];
        int b = p >> 22;
        bbuf[gofs[b] + i] = p & 0x3FFFFFu;
    }
}

// 1 block per bucket: (node,slice) counting sort -> col + rowptr2[n][8]
__global__ __launch_bounds__(256) void k_build(const int* __restrict__ btotal, const int* __restrict__ bbase,
                                               const unsigned int* __restrict__ bbuf,
                                               int* __restrict__ rowptr2, int* __restrict__ col) {
    const int b = blockIdx.x;
    const int t = threadIdx.x;
    const int cnt = btotal[b];
    const int base = bbase[b];
    const int node0 = b << 6;

    __shared__ unsigned int s_e[BCAP];
    __shared__ int s_cnt[512];   // key = (node&63)*8 + slice, slice in 0..6 (7 empty)
    __shared__ int s_cur[512];
    __shared__ int s_scan[256];

    s_cnt[t] = 0; s_cnt[t + 256] = 0;
    __syncthreads();
    for (int i = t; i < cnt; i += 256) {
        unsigned int p = bbuf[(size_t)base + i];
        s_e[i] = p;
        int key = (int)((p >> 16) & 63) * 8 + (int)((p & 0xFFFFu) >> 13);
        atomicAdd(&s_cnt[key], 1);
    }
    __syncthreads();
    // exclusive scan of 512 (2 per thread)
    int v0 = s_cnt[t * 2], v1 = s_cnt[t * 2 + 1];
    int sum = v0 + v1;
    s_scan[t] = sum;
    __syncthreads();
    for (int off = 1; off < 256; off <<= 1) {
        int add = (t >= off) ? s_scan[t - off] : 0;
        __syncthreads();
        s_scan[t] += add;
        __syncthreads();
    }
    int run = s_scan[t] - sum;
    s_cur[t * 2] = run;
    s_cur[t * 2 + 1] = run + v0;
    __syncthreads();
    // rowptr2: all 512 slots; slot (node,7) == row end (slice 7 never occupied)
    {
        int key0 = t * 2, key1 = t * 2 + 1;
        int n0 = node0 + (key0 >> 3);
        int n1 = node0 + (key1 >> 3);
        if (n0 < N_NODES) rowptr2[(size_t)n0 * RP2W + (key0 & 7)] = base + s_cur[key0];
        if (n1 < N_NODES) rowptr2[(size_t)n1 * RP2W + (key1 & 7)] = base + s_cur[key1];
    }
    __syncthreads();
    for (int i = t; i < cnt; i += 256) {
        unsigned int p = s_e[i];
        int key = (int)((p >> 16) & 63) * 8 + (int)((p & 0xFFFFu) >> 13);
        int pos = atomicAdd(&s_cur[key], 1);
        col[base + pos] = (int)(p & 0xFFFFu);
    }
}

// ---------------- dtype prep ----------------

__global__ void k_quant(const float* __restrict__ x, ushort* __restrict__ xb, int n4) {
    int i = blockIdx.x * 256 + threadIdx.x;
    if (i >= n4) return;
    float4 v = ((const float4*)x)[i];
    ushort4 o;
    o.x = f2b(v.x); o.y = f2b(v.y); o.z = f2b(v.z); o.w = f2b(v.w);
    ((ushort4*)xb)[i] = o;
}

__global__ void k_wt(const float* __restrict__ W, ushort* __restrict__ Wt) {
    int i = blockIdx.x * 256 + threadIdx.x;  // 65536
    int k = i >> 8, n = i & 255;
    Wt[n * 256 + k] = f2b(W[i]);
}

__global__ void k_wtc(const float* __restrict__ W2, const float* __restrict__ Wl, ushort* __restrict__ Wt) {
    int i = blockIdx.x * 256 + threadIdx.x;  // 65536
    int k = i >> 8, n = i & 255;
    float v = (n < 128) ? W2[k * 128 + n] : Wl[k * 128 + (n - 128)];
    Wt[n * 256 + k] = f2b(v);
}

// ---------------- bf16 MFMA GEMM (+fused attention logits for layers 0/1) ----------------

template <bool FUSE>
__global__ __launch_bounds__(256) void k_mfma(const ushort* __restrict__ A, const ushort* __restrict__ Bt,
                                              ushort* __restrict__ Cb, int M,
                                              const float* __restrict__ a_s, const float* __restrict__ a_d,
                                              float* __restrict__ als, float* __restrict__ ald) {
    const int t = threadIdx.x;
    const int w = t >> 6, l = t & 63;
    const int lr = l & 15, lk = l >> 4;
    const int m0 = blockIdx.x * 32;
    const int n0 = w * 64;
    f32x4 acc[2][4] = {};

    int r0 = m0 + lr;      if (r0 >= M) r0 = M - 1;
    int r1 = m0 + 16 + lr; if (r1 >= M) r1 = M - 1;
    const ushort* a0p = A + (size_t)r0 * 256 + lk * 8;
    const ushort* a1p = A + (size_t)r1 * 256 + lk * 8;
    const ushort* bp  = Bt + (size_t)(n0 + lr) * 256 + lk * 8;

#pragma unroll
    for (int k0 = 0; k0 < 256; k0 += 32) {
        bf16x8 a0 = *(const bf16x8*)(a0p + k0);
        bf16x8 a1 = *(const bf16x8*)(a1p + k0);
#pragma unroll
        for (int n = 0; n < 4; ++n) {
            bf16x8 b = *(const bf16x8*)(bp + n * 16 * 256 + k0);
            acc[0][n] = __builtin_amdgcn_mfma_f32_16x16x32_bf16(a0, b, acc[0][n], 0, 0, 0);
            acc[1][n] = __builtin_amdgcn_mfma_f32_16x16x32_bf16(a1, b, acc[1][n], 0, 0, 0);
        }
    }

#pragma unroll
    for (int m = 0; m < 2; ++m) {
#pragma unroll
        for (int r = 0; r < 4; ++r) {
            int row = m0 + m * 16 + lk * 4 + r;
            if (row >= M) continue;
#pragma unroll
            for (int n = 0; n < 4; ++n) {
                Cb[(size_t)row * 256 + n0 + n * 16 + lr] = f2b(acc[m][n][r]);
            }
        }
    }

    if constexpr (FUSE) {
        float asc[4], adc[4];
#pragma unroll
        for (int n = 0; n < 4; ++n) {
            int c = n0 + n * 16 + lr;
            asc[n] = a_s[c];
            adc[n] = a_d[c];
        }
#pragma unroll
        for (int m = 0; m < 2; ++m) {
#pragma unroll
            for (int r = 0; r < 4; ++r) {
                float pa = 0.f, pd = 0.f;
#pragma unroll
                for (int n = 0; n < 4; ++n) {
                    pa += acc[m][n][r] * asc[n];
                    pd += acc[m][n][r] * adc[n];
                }
#pragma unroll
                for (int off = 1; off < 16; off <<= 1) {
                    pa += __shfl_xor(pa, off);
                    pd += __shfl_xor(pd, off);
                }
                if (lr == 0) {
                    int row = m0 + m * 16 + lk * 4 + r;
                    if (row < M) {
                        als[row * 4 + w] = pa;
                        ald[row * 4 + w] = pd;
                    }
                }
            }
        }
    }
}

// ---------------- attention logits (layer 2 only) ----------------

template <int HEADS, int CHAN>
__global__ __launch_bounds__(256) void k_al(const ushort* __restrict__ Pb,
                                            const float* __restrict__ a_s, const float* __restrict__ a_d,
                                            float* __restrict__ als, float* __restrict__ ald) {
    int n = blockIdx.x * 4 + (threadIdx.x >> 6);
    if (n >= N_NODES) return;
    int l = threadIdx.x & 63;
    const ushort* row = Pb + (size_t)n * 256;
#pragma unroll
    for (int h = 0; h < HEADS; ++h) {
        float ps = 0.f, pd = 0.f;
#pragma unroll
        for (int c = l; c < CHAN; c += 64) {
            float v = b2f(row[h * CHAN + c]);
            ps += v * a_s[h * CHAN + c];
            pd += v * a_d[h * CHAN + c];
        }
#pragma unroll
        for (int off = 32; off > 0; off >>= 1) {
            ps += __shfl_xor(ps, off);
            pd += __shfl_xor(pd, off);
        }
        if (l == 0) { als[n * HEADS + h] = ps; ald[n * HEADS + h] = pd; }
    }
}

// ---------------- aggregation: slice-swept wave-per-node gather (LDS-free) ----------------
// Wave wid owns nodes {wid + k*WPG}. Outer loop over NS src-slices: all waves gather
// from one 4 MB L2-resident slice at a time. Per edge each lane recomputes its own
// head's weight from L2-hot als; denominator sw needs no reduce (every lane sees
// every edge). No max subtraction (logits O(1), softmax shift-invariant).

template <int HEADS, int CPL, bool RESB, bool LIN, bool WRITEF, bool WRITEB>
__global__ __launch_bounds__(256) void k_aggp(
    const ushort* __restrict__ Pb,
    const float* __restrict__ als, const float* __restrict__ ald,
    const int* __restrict__ rowptr2, const int* __restrict__ col,
    const float* __restrict__ bias, const float* __restrict__ bias2,
    const ushort* __restrict__ residb, float* __restrict__ out, ushort* __restrict__ outb) {
    constexpr int BLK = 64 * CPL;
    const int t = threadIdx.x;
    const int w = t >> 6, l = t & 63;
    const int wid = blockIdx.x * 4 + w;          // 0..WPG-1
    const int hsel = (HEADS == 4) ? (l >> 4) : 0;

    float acc[NPW][CPL];
    float sw[NPW];
    float aldk[NPW];
#pragma unroll
    for (int k = 0; k < NPW; ++k) {
        sw[k] = 0.f;
#pragma unroll
        for (int c = 0; c < CPL; ++c) acc[k][c] = 0.f;
        int n = wid + k * WPG;
        aldk[k] = (n < N_NODES) ? ald[(size_t)n * HEADS + hsel] : 0.f;
    }

    for (int s = 0; s < NS; ++s) {
#pragma unroll
        for (int k = 0; k < NPW; ++k) {
            int n = wid + k * WPG;
            if (n >= N_NODES) continue;
            int e  = __builtin_amdgcn_readfirstlane(rowptr2[(size_t)n * RP2W + s]);
            int ee = __builtin_amdgcn_readfirstlane(rowptr2[(size_t)n * RP2W + s + 1]);
            for (; e + 2 <= ee; e += 2) {
                int s0 = __builtin_amdgcn_readfirstlane(col[e]);
                int s1 = __builtin_amdgcn_readfirstlane(col[e + 1]);
                float w0 = __expf(lrelu(als[(size_t)s0 * HEADS + hsel] + aldk[k]));
                float w1 = __expf(lrelu(als[(size_t)s1 * HEADS + hsel] + aldk[k]));
                if constexpr (CPL == 4) {
                    uint2 v0 = *(const uint2*)(Pb + (size_t)s0 * 256 + l * 4);
                    uint2 v1 = *(const uint2*)(Pb + (size_t)s1 * 256 + l * 4);
                    acc[k][0] += w0 * lo2f(v0.x); acc[k][1] += w0 * hi2f(v0.x);
                    acc[k][2] += w0 * lo2f(v0.y); acc[k][3] += w0 * hi2f(v0.y);
                    acc[k][0] += w1 * lo2f(v1.x); acc[k][1] += w1 * hi2f(v1.x);
                    acc[k][2] += w1 * lo2f(v1.y); acc[k][3] += w1 * hi2f(v1.y);
                } else {
                    unsigned int v0 = *(const unsigned int*)(Pb + (size_t)s0 * 256 + l * 2);
                    unsigned int v1 = *(const unsigned int*)(Pb + (size_t)s1 * 256 + l * 2);
                    acc[k][0] += w0 * lo2f(v0); acc[k][1] += w0 * hi2f(v0);
                    acc[k][0] += w1 * lo2f(v1); acc[k][1] += w1 * hi2f(v1);
                }
                sw[k] += w0 + w1;
            }
            if (e < ee) {
                int s0 = __builtin_amdgcn_readfirstlane(col[e]);
                float w0 = __expf(lrelu(als[(size_t)s0 * HEADS + hsel] + aldk[k]));
                if constexpr (CPL == 4) {
                    uint2 v0 = *(const uint2*)(Pb + (size_t)s0 * 256 + l * 4);
                    acc[k][0] += w0 * lo2f(v0.x); acc[k][1] += w0 * hi2f(v0.x);
                    acc[k][2] += w0 * lo2f(v0.y); acc[k][3] += w0 * hi2f(v0.y);
                } else {
                    unsigned int v0 = *(const unsigned int*)(Pb + (size_t)s0 * 256 + l * 2);
                    acc[k][0] += w0 * lo2f(v0); acc[k][1] += w0 * hi2f(v0);
                }
                sw[k] += w0;
            }
        }
    }

#pragma unroll
    for (int k = 0; k < NPW; ++k) {
        int n = wid + k * WPG;
        if (n >= N_NODES) continue;
        float rinv = 1.0f / sw[k];
        float r[CPL];
#pragma unroll
        for (int c = 0; c < CPL; ++c) r[c] = acc[k][c] * rinv + bias[l * CPL + c];
        if constexpr (RESB) {
            ushort4 rv = *(const ushort4*)(residb + (size_t)n * 256 + l * 4);
            r[0] += b2f(rv.x); r[1] += b2f(rv.y); r[2] += b2f(rv.z); r[3] += b2f(rv.w);
        }
        if constexpr (LIN) {
            unsigned int lv = *(const unsigned int*)(Pb + (size_t)n * 256 + 128 + l * 2);
            float2 bv = *(const float2*)(bias2 + l * 2);
            r[0] += lo2f(lv) + bv.x;
            r[1] += hi2f(lv) + bv.y;
        }
        if constexpr (WRITEF) {
            if constexpr (CPL == 4) {
                *(float4*)&out[(size_t)n * BLK + l * 4] = make_float4(r[0], r[1], r[2], r[3]);
            } else {
                *(float2*)&out[(size_t)n * BLK + l * 2] = make_float2(r[0], r[1]);
            }
        }
        if constexpr (WRITEB) {
            ushort4 o;
            o.x = f2b(r[0]); o.y = f2b(r[1]); o.z = f2b(r[2]); o.w = f2b(r[3]);
            *(ushort4*)&outb[(size_t)n * BLK + l * 4] = o;
        }
    }
}

// ---------------- launch ----------------

extern "C" void kernel_launch(void* const* d_in, const int* in_sizes, int n_in,
                              void* d_out, int out_size, void* d_ws, size_t ws_size,
                              hipStream_t stream) {
    const float* x   = (const float*)d_in[0];
    const int* ei    = (const int*)d_in[1];
    const int* esrc  = ei;
    const int* edst  = ei + N_EDGES;
    const float* W0  = (const float*)d_in[2];
    const float* as0 = (const float*)d_in[3];
    const float* ad0 = (const float*)d_in[4];
    const float* b0  = (const float*)d_in[5];
    const float* W1  = (const float*)d_in[6];
    const float* as1 = (const float*)d_in[7];
    const float* ad1 = (const float*)d_in[8];
    const float* b1  = (const float*)d_in[9];
    const float* W2  = (const float*)d_in[10];
    const float* as2 = (const float*)d_in[11];
    const float* ad2 = (const float*)d_in[12];
    const float* b2  = (const float*)d_in[13];
    const float* Wl  = (const float*)d_in[14];
    const float* bl  = (const float*)d_in[15];
    float* out = (float*)d_out;

    char* w = (char*)d_ws;
    auto alloc = [&](size_t bytes) { char* p = w; w += (bytes + 255) & ~(size_t)255; return p; };
    ushort* xb  = (ushort*)alloc((size_t)N_NODES * 256 * 2);  // reused as h1b
    ushort* Pb  = (ushort*)alloc((size_t)N_NODES * 256 * 2);
    ushort* h0b = (ushort*)alloc((size_t)N_NODES * 256 * 2);
    float* als = (float*)alloc((size_t)N_NODES * 4 * 4);
    float* ald = (float*)alloc((size_t)N_NODES * 4 * 4);
    ushort* Wt0 = (ushort*)alloc(256 * 256 * 2);
    ushort* Wt1 = (ushort*)alloc(256 * 256 * 2);
    ushort* Wtc = (ushort*)alloc(256 * 256 * 2);
    unsigned int* bbuf = (unsigned int*)alloc((size_t)E2 * 4);
    int* hist   = (int*)alloc((size_t)NBLK_E * NB * 4);
    int* start  = (int*)alloc((size_t)NBLK_E * NB * 4);
    int* btotal = (int*)alloc((size_t)NB * 4);
    int* bbase  = (int*)alloc((size_t)NB * 4);
    int* rowptr2 = (int*)alloc((size_t)N_NODES * RP2W * 4);
    int* colb   = (int*)alloc((size_t)E2 * 4);
    ushort* h1b = xb;

    // CSR build (atomic-free bucket sort, slice-grouped rows)
    k_bhist<<<NBLK_E, 256, 0, stream>>>(edst, hist);
    k_colscan<<<1, 1024, 0, stream>>>(hist, start, btotal);
    k_bscan<<<1, 256, 0, stream>>>(btotal, bbase);
    k_bscatter<<<NBLK_E, 256, 0, stream>>>(esrc, edst, start, bbase, bbuf);
    k_build<<<NB, 256, 0, stream>>>(btotal, bbase, bbuf, rowptr2, colb);

    k_quant<<<(N_NODES * 256 / 4 + 255) / 256, 256, 0, stream>>>(x, xb, N_NODES * 256 / 4);
    k_wt<<<256, 256, 0, stream>>>(W0, Wt0);
    k_wt<<<256, 256, 0, stream>>>(W1, Wt1);
    k_wtc<<<256, 256, 0, stream>>>(W2, Wl, Wtc);

    const int gm = (N_NODES + 31) / 32;
    const int ga = (N_NODES + 3) / 4;
    const int gp = WPG / 4;  // 2048 blocks

    // layer 0 (GEMM + fused attention logits)
    k_mfma<true><<<gm, 256, 0, stream>>>(xb, Wt0, Pb, N_NODES, as0, ad0, als, ald);
    k_aggp<4, 4, false, false, false, true><<<gp, 256, 0, stream>>>(
        Pb, als, ald, rowptr2, colb, b0, nullptr, nullptr, nullptr, h0b);
    // layer 1
    k_mfma<true><<<gm, 256, 0, stream>>>(h0b, Wt1, Pb, N_NODES, as1, ad1, als, ald);
    k_aggp<4, 4, true, false, false, true><<<gp, 256, 0, stream>>>(
        Pb, als, ald, rowptr2, colb, b1, nullptr, h0b, nullptr, h1b);
    // layer 2: GEMM -> [h1@W2 | h1@Wl] all bf16 in Pb
    k_mfma<false><<<gm, 256, 0, stream>>>(h1b, Wtc, Pb, N_NODES, nullptr, nullptr, nullptr, nullptr);
    k_al<1, 128><<<ga, 256, 0, stream>>>(Pb, as2, ad2, als, ald);
    k_aggp<1, 2, false, true, true, false><<<gp, 256, 0, stream>>>(
        Pb, als, ald, rowptr2, colb, b2, bl, nullptr, out, nullptr);
}

// Round 10
// 644.932 us; speedup vs baseline: 1.1464x; 1.1464x over previous
//
#include <hip/hip_runtime.h>
#include <hip/hip_bf16.h>

#define N_NODES 50000
#define N_EDGES 1600000
#define E2 (N_EDGES + N_NODES)
#define NB 782      // buckets of 64 dst nodes
#define BCAP 3072   // max edges per bucket (mean 2112, 21 sigma)
#define CHUNK 8192
#define NBLK_E 202  // ceil(E2 / CHUNK)
#define NS 7        // src slices of 8192 nodes (4 MB bf16 rows = one XCD L2)
#define RP2W 8      // rowptr2 row width: starts of s=0..6, slot 7 = row end

typedef __attribute__((ext_vector_type(8))) short bf16x8;
typedef __attribute__((ext_vector_type(4))) float f32x4;

static __device__ __forceinline__ float lrelu(float x) { return x > 0.f ? x : 0.2f * x; }

static __device__ __forceinline__ float b2f(ushort u) {
    union { unsigned int u; float f; } v;
    v.u = ((unsigned int)u) << 16;
    return v.f;
}
static __device__ __forceinline__ float hi2f(unsigned int u) {
    union { unsigned int u; float f; } v;
    v.u = u & 0xffff0000u;
    return v.f;
}
static __device__ __forceinline__ float lo2f(unsigned int u) {
    union { unsigned int u; float f; } v;
    v.u = u << 16;
    return v.f;
}
static __device__ __forceinline__ ushort f2b(float f) {
    union { float f; unsigned int u; } v;
    v.f = f;
    unsigned int r = v.u + 0x7FFFu + ((v.u >> 16) & 1u);  // RNE
    return (ushort)(r >> 16);
}

// ---------------- CSR build: atomic-free 3-pass bucket sort ----------------

__global__ __launch_bounds__(256) void k_bhist(const int* __restrict__ edst, int* __restrict__ hist) {
    __shared__ int cnt[NB];
    int t = threadIdx.x;
    for (int i = t; i < NB; i += 256) cnt[i] = 0;
    __syncthreads();
    int e0 = blockIdx.x * CHUNK;
    int eend = min(e0 + CHUNK, E2);
    for (int e = e0 + t; e < eend; e += 256) {
        int d = (e < N_EDGES) ? edst[e] : (e - N_EDGES);
        atomicAdd(&cnt[d >> 6], 1);
    }
    __syncthreads();
    for (int i = t; i < NB; i += 256) hist[blockIdx.x * NB + i] = cnt[i];
}

__global__ __launch_bounds__(1024) void k_colscan(const int* __restrict__ hist,
                                                  int* __restrict__ start, int* __restrict__ btotal) {
    int b = threadIdx.x;
    if (b >= NB) return;
    int run = 0;
#pragma unroll 4
    for (int blk = 0; blk < NBLK_E; ++blk) {
        int v = hist[blk * NB + b];
        start[blk * NB + b] = run;
        run += v;
    }
    btotal[b] = run;
}

__global__ __launch_bounds__(256) void k_bscan(const int* __restrict__ btotal, int* __restrict__ bbase) {
    __shared__ int s[256];
    int t = threadIdx.x;
    int v[4];
    int sum = 0;
#pragma unroll
    for (int k = 0; k < 4; ++k) {
        int i = t * 4 + k;
        v[k] = (i < NB) ? btotal[i] : 0;
        sum += v[k];
    }
    s[t] = sum;
    __syncthreads();
    for (int off = 1; off < 256; off <<= 1) {
        int add = (t >= off) ? s[t - off] : 0;
        __syncthreads();
        s[t] += add;
        __syncthreads();
    }
    int base = s[t] - sum;
#pragma unroll
    for (int k = 0; k < 4; ++k) {
        int i = t * 4 + k;
        if (i < NB) bbase[i] = base;
        base += v[k];
    }
}

__global__ __launch_bounds__(256) void k_bscatter(const int* __restrict__ esrc, const int* __restrict__ edst,
                                                  const int* __restrict__ start, const int* __restrict__ bbase,
                                                  unsigned int* __restrict__ bbuf) {
    __shared__ int cnt[NB];
    __shared__ int cur[NB];
    __shared__ int gofs[NB];
    __shared__ int s_scan[256];
    __shared__ unsigned int s_e[CHUNK];
    int t = threadIdx.x;
    for (int i = t; i < NB; i += 256) cnt[i] = 0;
    __syncthreads();
    int e0 = blockIdx.x * CHUNK;
    int eend = min(e0 + CHUNK, E2);
    for (int e = e0 + t; e < eend; e += 256) {
        int d = (e < N_EDGES) ? edst[e] : (e - N_EDGES);
        atomicAdd(&cnt[d >> 6], 1);
    }
    __syncthreads();
    int v[4];
    int sum = 0;
#pragma unroll
    for (int k = 0; k < 4; ++k) {
        int i = t * 4 + k;
        v[k] = (i < NB) ? cnt[i] : 0;
        sum += v[k];
    }
    s_scan[t] = sum;
    __syncthreads();
    for (int off = 1; off < 256; off <<= 1) {
        int add = (t >= off) ? s_scan[t - off] : 0;
        __syncthreads();
        s_scan[t] += add;
        __syncthreads();
    }
    int run = s_scan[t] - sum;
#pragma unroll
    for (int k = 0; k < 4; ++k) {
        int i = t * 4 + k;
        if (i < NB) {
            cur[i] = run;
            gofs[i] = bbase[i] + start[blockIdx.x * NB + i] - run;
        }
        run += v[k];
    }
    __syncthreads();
    for (int e = e0 + t; e < eend; e += 256) {
        int s, d;
        if (e < N_EDGES) { s = esrc[e]; d = edst[e]; } else { s = d = e - N_EDGES; }
        int b = d >> 6;
        int pos = atomicAdd(&cur[b], 1);
        s_e[pos] = (unsigned int)s | ((unsigned int)(d & 63) << 16) | ((unsigned int)b << 22);
    }
    __syncthreads();
    int cntall = eend - e0;
    for (int i = t; i < cntall; i += 256) {
        unsigned int p = s_e[i];
        int b = p >> 22;
        bbuf[gofs[b] + i] = p & 0x3FFFFFu;
    }
}

// 1 block per bucket: (node,slice) counting sort -> col (slice-sorted rows) + rowptr2[n][8]
__global__ __launch_bounds__(256) void k_build(const int* __restrict__ btotal, const int* __restrict__ bbase,
                                               const unsigned int* __restrict__ bbuf,
                                               int* __restrict__ rowptr2, int* __restrict__ col) {
    const int b = blockIdx.x;
    const int t = threadIdx.x;
    const int cnt = btotal[b];
    const int base = bbase[b];
    const int node0 = b << 6;

    __shared__ unsigned int s_e[BCAP];
    __shared__ int s_cnt[512];   // key = (node&63)*8 + slice, slice in 0..6 (7 empty)
    __shared__ int s_cur[512];
    __shared__ int s_scan[256];

    s_cnt[t] = 0; s_cnt[t + 256] = 0;
    __syncthreads();
    for (int i = t; i < cnt; i += 256) {
        unsigned int p = bbuf[(size_t)base + i];
        s_e[i] = p;
        int key = (int)((p >> 16) & 63) * 8 + (int)((p & 0xFFFFu) >> 13);
        atomicAdd(&s_cnt[key], 1);
    }
    __syncthreads();
    int v0 = s_cnt[t * 2], v1 = s_cnt[t * 2 + 1];
    int sum = v0 + v1;
    s_scan[t] = sum;
    __syncthreads();
    for (int off = 1; off < 256; off <<= 1) {
        int add = (t >= off) ? s_scan[t - off] : 0;
        __syncthreads();
        s_scan[t] += add;
        __syncthreads();
    }
    int run = s_scan[t] - sum;
    s_cur[t * 2] = run;
    s_cur[t * 2 + 1] = run + v0;
    __syncthreads();
    {
        int key0 = t * 2, key1 = t * 2 + 1;
        int n0 = node0 + (key0 >> 3);
        int n1 = node0 + (key1 >> 3);
        if (n0 < N_NODES) rowptr2[(size_t)n0 * RP2W + (key0 & 7)] = base + s_cur[key0];
        if (n1 < N_NODES) rowptr2[(size_t)n1 * RP2W + (key1 & 7)] = base + s_cur[key1];
    }
    __syncthreads();
    for (int i = t; i < cnt; i += 256) {
        unsigned int p = s_e[i];
        int key = (int)((p >> 16) & 63) * 8 + (int)((p & 0xFFFFu) >> 13);
        int pos = atomicAdd(&s_cur[key], 1);
        col[base + pos] = (int)(p & 0xFFFFu);
    }
}

// ---------------- dtype prep ----------------

__global__ void k_quant(const float* __restrict__ x, ushort* __restrict__ xb, int n4) {
    int i = blockIdx.x * 256 + threadIdx.x;
    if (i >= n4) return;
    float4 v = ((const float4*)x)[i];
    ushort4 o;
    o.x = f2b(v.x); o.y = f2b(v.y); o.z = f2b(v.z); o.w = f2b(v.w);
    ((ushort4*)xb)[i] = o;
}

__global__ void k_wt(const float* __restrict__ W, ushort* __restrict__ Wt) {
    int i = blockIdx.x * 256 + threadIdx.x;  // 65536
    int k = i >> 8, n = i & 255;
    Wt[n * 256 + k] = f2b(W[i]);
}

__global__ void k_wtc(const float* __restrict__ W2, const float* __restrict__ Wl, ushort* __restrict__ Wt) {
    int i = blockIdx.x * 256 + threadIdx.x;  // 65536
    int k = i >> 8, n = i & 255;
    float v = (n < 128) ? W2[k * 128 + n] : Wl[k * 128 + (n - 128)];
    Wt[n * 256 + k] = f2b(v);
}

// ---------------- bf16 MFMA GEMM (+fused attention logits for layers 0/1) ----------------

template <bool FUSE>
__global__ __launch_bounds__(256) void k_mfma(const ushort* __restrict__ A, const ushort* __restrict__ Bt,
                                              ushort* __restrict__ Cb, int M,
                                              const float* __restrict__ a_s, const float* __restrict__ a_d,
                                              float* __restrict__ als, float* __restrict__ ald) {
    const int t = threadIdx.x;
    const int w = t >> 6, l = t & 63;
    const int lr = l & 15, lk = l >> 4;
    const int m0 = blockIdx.x * 32;
    const int n0 = w * 64;
    f32x4 acc[2][4] = {};

    int r0 = m0 + lr;      if (r0 >= M) r0 = M - 1;
    int r1 = m0 + 16 + lr; if (r1 >= M) r1 = M - 1;
    const ushort* a0p = A + (size_t)r0 * 256 + lk * 8;
    const ushort* a1p = A + (size_t)r1 * 256 + lk * 8;
    const ushort* bp  = Bt + (size_t)(n0 + lr) * 256 + lk * 8;

#pragma unroll
    for (int k0 = 0; k0 < 256; k0 += 32) {
        bf16x8 a0 = *(const bf16x8*)(a0p + k0);
        bf16x8 a1 = *(const bf16x8*)(a1p + k0);
#pragma unroll
        for (int n = 0; n < 4; ++n) {
            bf16x8 b = *(const bf16x8*)(bp + n * 16 * 256 + k0);
            acc[0][n] = __builtin_amdgcn_mfma_f32_16x16x32_bf16(a0, b, acc[0][n], 0, 0, 0);
            acc[1][n] = __builtin_amdgcn_mfma_f32_16x16x32_bf16(a1, b, acc[1][n], 0, 0, 0);
        }
    }

#pragma unroll
    for (int m = 0; m < 2; ++m) {
#pragma unroll
        for (int r = 0; r < 4; ++r) {
            int row = m0 + m * 16 + lk * 4 + r;
            if (row >= M) continue;
#pragma unroll
            for (int n = 0; n < 4; ++n) {
                Cb[(size_t)row * 256 + n0 + n * 16 + lr] = f2b(acc[m][n][r]);
            }
        }
    }

    if constexpr (FUSE) {
        float asc[4], adc[4];
#pragma unroll
        for (int n = 0; n < 4; ++n) {
            int c = n0 + n * 16 + lr;
            asc[n] = a_s[c];
            adc[n] = a_d[c];
        }
#pragma unroll
        for (int m = 0; m < 2; ++m) {
#pragma unroll
            for (int r = 0; r < 4; ++r) {
                float pa = 0.f, pd = 0.f;
#pragma unroll
                for (int n = 0; n < 4; ++n) {
                    pa += acc[m][n][r] * asc[n];
                    pd += acc[m][n][r] * adc[n];
                }
#pragma unroll
                for (int off = 1; off < 16; off <<= 1) {
                    pa += __shfl_xor(pa, off);
                    pd += __shfl_xor(pd, off);
                }
                if (lr == 0) {
                    int row = m0 + m * 16 + lk * 4 + r;
                    if (row < M) {
                        als[row * 4 + w] = pa;
                        ald[row * 4 + w] = pd;
                    }
                }
            }
        }
    }
}

// ---------------- attention logits (layer 2 only) ----------------

template <int HEADS, int CHAN>
__global__ __launch_bounds__(256) void k_al(const ushort* __restrict__ Pb,
                                            const float* __restrict__ a_s, const float* __restrict__ a_d,
                                            float* __restrict__ als, float* __restrict__ ald) {
    int n = blockIdx.x * 4 + (threadIdx.x >> 6);
    if (n >= N_NODES) return;
    int l = threadIdx.x & 63;
    const ushort* row = Pb + (size_t)n * 256;
#pragma unroll
    for (int h = 0; h < HEADS; ++h) {
        float ps = 0.f, pd = 0.f;
#pragma unroll
        for (int c = l; c < CHAN; c += 64) {
            float v = b2f(row[h * CHAN + c]);
            ps += v * a_s[h * CHAN + c];
            pd += v * a_d[h * CHAN + c];
        }
#pragma unroll
        for (int off = 32; off > 0; off >>= 1) {
            ps += __shfl_xor(ps, off);
            pd += __shfl_xor(pd, off);
        }
        if (l == 0) { als[n * HEADS + h] = ps; ald[n * HEADS + h] = pd; }
    }
}

// ---------------- helpers ----------------

template <int HEADS>
__device__ __forceinline__ void load_als(const float* __restrict__ als, int src, float* v) {
    if constexpr (HEADS == 4) {
        float4 a = *(const float4*)(als + (size_t)src * 4);
        v[0] = a.x; v[1] = a.y; v[2] = a.z; v[3] = a.w;
    } else {
        v[0] = als[src];
    }
}

// ---------------- softmax + aggregation: one WAVE per dst node ----------------
// Round-8 structure (LDS-staged, wave-per-node, no barriers) over the slice-sorted
// col array: concurrent waves advance through src slices roughly in phase -> soft
// L2 blocking with full memory parallelism. Pb row stride is ALWAYS 256.

template <int HEADS, int CHAN, bool RESB, bool LIN, bool WRITEF, bool WRITEB>
__global__ __launch_bounds__(256) void k_aggw(
    const ushort* __restrict__ Pb,
    const float* __restrict__ als, const float* __restrict__ ald,
    const int* __restrict__ rowptr2, const int* __restrict__ col,
    const float* __restrict__ bias, const float* __restrict__ bias2,
    const ushort* __restrict__ residb, float* __restrict__ out, ushort* __restrict__ outb) {
    constexpr int BLK = HEADS * CHAN;
    constexpr int CPL = BLK / 64;       // channels per lane: 4 (layers 0/1) or 2 (layer 2)
    const int t = threadIdx.x;
    const int w = t >> 6, l = t & 63;
    const int n = blockIdx.x * 4 + w;   // grid is exactly N/4
    const int rs = rowptr2[(size_t)n * RP2W];
    const int deg = rowptr2[(size_t)n * RP2W + NS] - rs;

    __shared__ int s_src[4][64];
    __shared__ float s_w[4][64 * HEADS];

    float aldn[HEADS];
    load_als<HEADS>(ald, n, aldn);

    float acc[CPL];
#pragma unroll
    for (int c = 0; c < CPL; ++c) acc[c] = 0.f;
    float sw[HEADS];
#pragma unroll
    for (int h = 0; h < HEADS; ++h) sw[h] = 0.f;

    const int hsel = l >> 4;  // head of this lane's channels (HEADS==4 case)

    for (int base = 0; base < deg; base += 64) {
        int j = base + l;
        if (j < deg) {
            int src = col[rs + j];
            s_src[w][l] = src;
            float av[HEADS];
            load_als<HEADS>(als, src, av);
#pragma unroll
            for (int h = 0; h < HEADS; ++h) {
                float wv = __expf(lrelu(av[h] + aldn[h]));
                s_w[w][l * HEADS + h] = wv;
                sw[h] += wv;
            }
        }
        int cnt = min(64, deg - base);
        int jj = 0;
        for (; jj + 2 <= cnt; jj += 2) {
            int s0 = __builtin_amdgcn_readfirstlane(s_src[w][jj]);
            int s1 = __builtin_amdgcn_readfirstlane(s_src[w][jj + 1]);
            if constexpr (CPL == 4) {
                float w0 = s_w[w][jj * HEADS + hsel];
                float w1 = s_w[w][(jj + 1) * HEADS + hsel];
                uint2 v0 = *(const uint2*)(Pb + (size_t)s0 * 256 + l * 4);
                uint2 v1 = *(const uint2*)(Pb + (size_t)s1 * 256 + l * 4);
                acc[0] += w0 * lo2f(v0.x); acc[1] += w0 * hi2f(v0.x);
                acc[2] += w0 * lo2f(v0.y); acc[3] += w0 * hi2f(v0.y);
                acc[0] += w1 * lo2f(v1.x); acc[1] += w1 * hi2f(v1.x);
                acc[2] += w1 * lo2f(v1.y); acc[3] += w1 * hi2f(v1.y);
            } else {
                float w0 = s_w[w][jj];
                float w1 = s_w[w][jj + 1];
                unsigned int v0 = *(const unsigned int*)(Pb + (size_t)s0 * 256 + l * 2);
                unsigned int v1 = *(const unsigned int*)(Pb + (size_t)s1 * 256 + l * 2);
                acc[0] += w0 * lo2f(v0); acc[1] += w0 * hi2f(v0);
                acc[0] += w1 * lo2f(v1); acc[1] += w1 * hi2f(v1);
            }
        }
        if (jj < cnt) {
            int s0 = __builtin_amdgcn_readfirstlane(s_src[w][jj]);
            if constexpr (CPL == 4) {
                float w0 = s_w[w][jj * HEADS + hsel];
                uint2 v0 = *(const uint2*)(Pb + (size_t)s0 * 256 + l * 4);
                acc[0] += w0 * lo2f(v0.x); acc[1] += w0 * hi2f(v0.x);
                acc[2] += w0 * lo2f(v0.y); acc[3] += w0 * hi2f(v0.y);
            } else {
                float w0 = s_w[w][jj];
                unsigned int v0 = *(const unsigned int*)(Pb + (size_t)s0 * 256 + l * 2);
                acc[0] += w0 * lo2f(v0); acc[1] += w0 * hi2f(v0);
            }
        }
    }

    // weight-sum: full-wave shuffle reduce
#pragma unroll
    for (int off = 32; off > 0; off >>= 1)
#pragma unroll
        for (int h = 0; h < HEADS; ++h) sw[h] += __shfl_xor(sw[h], off);

    float stot;
    if constexpr (HEADS == 4) {
        stot = (hsel == 0) ? sw[0] : (hsel == 1) ? sw[1] : (hsel == 2) ? sw[2] : sw[3];
    } else {
        stot = sw[0];
    }
    float rinv = 1.0f / stot;

    float r[CPL];
#pragma unroll
    for (int c = 0; c < CPL; ++c) r[c] = acc[c] * rinv + bias[l * CPL + c];
    if constexpr (RESB) {
        ushort4 rv = *(const ushort4*)(residb + (size_t)n * 256 + l * 4);
        r[0] += b2f(rv.x); r[1] += b2f(rv.y); r[2] += b2f(rv.z); r[3] += b2f(rv.w);
    }
    if constexpr (LIN) {
        unsigned int lv = *(const unsigned int*)(Pb + (size_t)n * 256 + 128 + l * 2);
        float2 bv = *(const float2*)(bias2 + l * 2);
        r[0] += lo2f(lv) + bv.x;
        r[1] += hi2f(lv) + bv.y;
    }
    if constexpr (WRITEF) {
        if constexpr (CPL == 4) {
            *(float4*)&out[(size_t)n * BLK + l * 4] = make_float4(r[0], r[1], r[2], r[3]);
        } else {
            *(float2*)&out[(size_t)n * BLK + l * 2] = make_float2(r[0], r[1]);
        }
    }
    if constexpr (WRITEB) {
        ushort4 o;
        o.x = f2b(r[0]); o.y = f2b(r[1]); o.z = f2b(r[2]); o.w = f2b(r[3]);
        *(ushort4*)&outb[(size_t)n * BLK + l * 4] = o;
    }
}

// ---------------- launch ----------------

extern "C" void kernel_launch(void* const* d_in, const int* in_sizes, int n_in,
                              void* d_out, int out_size, void* d_ws, size_t ws_size,
                              hipStream_t stream) {
    const float* x   = (const float*)d_in[0];
    const int* ei    = (const int*)d_in[1];
    const int* esrc  = ei;
    const int* edst  = ei + N_EDGES;
    const float* W0  = (const float*)d_in[2];
    const float* as0 = (const float*)d_in[3];
    const float* ad0 = (const float*)d_in[4];
    const float* b0  = (const float*)d_in[5];
    const float* W1  = (const float*)d_in[6];
    const float* as1 = (const float*)d_in[7];
    const float* ad1 = (const float*)d_in[8];
    const float* b1  = (const float*)d_in[9];
    const float* W2  = (const float*)d_in[10];
    const float* as2 = (const float*)d_in[11];
    const float* ad2 = (const float*)d_in[12];
    const float* b2  = (const float*)d_in[13];
    const float* Wl  = (const float*)d_in[14];
    const float* bl  = (const float*)d_in[15];
    float* out = (float*)d_out;

    char* w = (char*)d_ws;
    auto alloc = [&](size_t bytes) { char* p = w; w += (bytes + 255) & ~(size_t)255; return p; };
    ushort* xb  = (ushort*)alloc((size_t)N_NODES * 256 * 2);  // reused as h1b
    ushort* Pb  = (ushort*)alloc((size_t)N_NODES * 256 * 2);
    ushort* h0b = (ushort*)alloc((size_t)N_NODES * 256 * 2);
    float* als = (float*)alloc((size_t)N_NODES * 4 * 4);
    float* ald = (float*)alloc((size_t)N_NODES * 4 * 4);
    ushort* Wt0 = (ushort*)alloc(256 * 256 * 2);
    ushort* Wt1 = (ushort*)alloc(256 * 256 * 2);
    ushort* Wtc = (ushort*)alloc(256 * 256 * 2);
    unsigned int* bbuf = (unsigned int*)alloc((size_t)E2 * 4);
    int* hist   = (int*)alloc((size_t)NBLK_E * NB * 4);
    int* start  = (int*)alloc((size_t)NBLK_E * NB * 4);
    int* btotal = (int*)alloc((size_t)NB * 4);
    int* bbase  = (int*)alloc((size_t)NB * 4);
    int* rowptr2 = (int*)alloc((size_t)N_NODES * RP2W * 4);
    int* colb   = (int*)alloc((size_t)E2 * 4);
    ushort* h1b = xb;

    // CSR build (atomic-free bucket sort, slice-sorted rows)
    k_bhist<<<NBLK_E, 256, 0, stream>>>(edst, hist);
    k_colscan<<<1, 1024, 0, stream>>>(hist, start, btotal);
    k_bscan<<<1, 256, 0, stream>>>(btotal, bbase);
    k_bscatter<<<NBLK_E, 256, 0, stream>>>(esrc, edst, start, bbase, bbuf);
    k_build<<<NB, 256, 0, stream>>>(btotal, bbase, bbuf, rowptr2, colb);

    k_quant<<<(N_NODES * 256 / 4 + 255) / 256, 256, 0, stream>>>(x, xb, N_NODES * 256 / 4);
    k_wt<<<256, 256, 0, stream>>>(W0, Wt0);
    k_wt<<<256, 256, 0, stream>>>(W1, Wt1);
    k_wtc<<<256, 256, 0, stream>>>(W2, Wl, Wtc);

    const int gm = (N_NODES + 31) / 32;
    const int ga = (N_NODES + 3) / 4;
    const int gn = N_NODES / 4;  // 12500 exact

    // layer 0 (GEMM + fused attention logits)
    k_mfma<true><<<gm, 256, 0, stream>>>(xb, Wt0, Pb, N_NODES, as0, ad0, als, ald);
    k_aggw<4, 64, false, false, false, true><<<gn, 256, 0, stream>>>(
        Pb, als, ald, rowptr2, colb, b0, nullptr, nullptr, nullptr, h0b);
    // layer 1
    k_mfma<true><<<gm, 256, 0, stream>>>(h0b, Wt1, Pb, N_NODES, as1, ad1, als, ald);
    k_aggw<4, 64, true, false, false, true><<<gn, 256, 0, stream>>>(
        Pb, als, ald, rowptr2, colb, b1, nullptr, h0b, nullptr, h1b);
    // layer 2: GEMM -> [h1@W2 | h1@Wl] all bf16 in Pb
    k_mfma<false><<<gm, 256, 0, stream>>>(h1b, Wtc, Pb, N_NODES, nullptr, nullptr, nullptr, nullptr);
    k_al<1, 128><<<ga, 256, 0, stream>>>(Pb, as2, ad2, als, ald);
    k_aggw<1, 128, false, true, true, false><<<gn, 256, 0, stream>>>(
        Pb, als, ald, rowptr2, colb, b2, bl, nullptr, out, nullptr);
}